// Round 1
// baseline (505.968 us; speedup 1.0000x reference)
//
#include <hip/hip_runtime.h>
#include <cstdint>
#include <cstddef>

#define N 8192
#define DIN 128
#define DTH 256
#define DOUT 128
#define ROWCAP 256
#define LISTCAP 256

typedef float vfloat4 __attribute__((ext_vector_type(4)));

// ---------------- threefry2x32 with key (0, 42) --------------------------
__device__ __forceinline__ void threefry_0_42(uint32_t x0, uint32_t x1,
                                              uint32_t& o0, uint32_t& o1) {
  const uint32_t ks0 = 0u;
  const uint32_t ks1 = 42u;
  const uint32_t ks2 = 0x1BD11BDAu ^ 0u ^ 42u;
  x0 += ks0; x1 += ks1;
#define TF_R(r) { x0 += x1; x1 = (x1 << (r)) | (x1 >> (32 - (r))); x1 ^= x0; }
  TF_R(13) TF_R(15) TF_R(26) TF_R(6)
  x0 += ks1; x1 += ks2 + 1u;
  TF_R(17) TF_R(29) TF_R(16) TF_R(24)
  x0 += ks2; x1 += ks0 + 2u;
  TF_R(13) TF_R(15) TF_R(26) TF_R(6)
  x0 += ks0; x1 += ks1 + 3u;
  TF_R(17) TF_R(29) TF_R(16) TF_R(24)
  x0 += ks1; x1 += ks2 + 4u;
  TF_R(13) TF_R(15) TF_R(26) TF_R(6)
  x0 += ks2; x1 += ks0 + 5u;
#undef TF_R
  o0 = x0; o1 = x1;
}

__device__ __forceinline__ bool dropedge_keep(uint32_t t) {
  uint32_t y0, y1;
  threefry_0_42(0u, t, y0, y1);
  uint32_t bits = y0 ^ y1;
  float u = __uint_as_float((bits >> 9) | 0x3f800000u) - 1.0f;
  return u < 0.8f;
}

__device__ __forceinline__ unsigned short f2bf(float v) {
  uint32_t u = __float_as_uint(v);
  u += 0x7fffu + ((u >> 16) & 1u);     // round-to-nearest-even
  return (unsigned short)(u >> 16);
}

// ---------------- K1: fused bn_part + W pack -----------------------------
// blocks [0,64): BN partial sums; [64,256): Wc pack; [256,258): bc.
// (deg / nnz_cnt no longer need zeroing: k_main writes them per-row.)
__global__ __launch_bounds__(256) void k_pre(
    const float* __restrict__ H,
    const float* __restrict__ Wt, const float* __restrict__ bt,
    const float* __restrict__ Wo, const float* __restrict__ bo,
    float* __restrict__ part_s, float* __restrict__ part_s2,
    float* __restrict__ Wc, float* __restrict__ bc) {
  int b = blockIdx.x;
  int tid = threadIdx.x;
  if (b < 64) {
    __shared__ float ls[8][DIN];
    __shared__ float ls2[8][DIN];
    int rg = tid >> 5;
    int c4 = tid & 31;
    int rbase = b * 128;
    float s[4] = {0,0,0,0}, s2[4] = {0,0,0,0};
    for (int k = 0; k < 16; ++k) {
      int r = rbase + rg + k * 8;
      float4 h = ((const float4*)(H + (size_t)r * DIN))[c4];
      s[0] += h.x; s2[0] += h.x * h.x;
      s[1] += h.y; s2[1] += h.y * h.y;
      s[2] += h.z; s2[2] += h.z * h.z;
      s[3] += h.w; s2[3] += h.w * h.w;
    }
#pragma unroll
    for (int q = 0; q < 4; ++q) { ls[rg][c4*4+q] = s[q]; ls2[rg][c4*4+q] = s2[q]; }
    __syncthreads();
    if (tid < DIN) {
      float a = 0.f, bb = 0.f;
#pragma unroll
      for (int g = 0; g < 8; ++g) { a += ls[g][tid]; bb += ls2[g][tid]; }
      part_s[b * DIN + tid] = a;
      part_s2[b * DIN + tid] = bb;
    }
  } else if (b < 256) {
    int idx = (b - 64) * 256 + tid;        // [0, 49152)
    int k = idx / 384, c = idx % 384;
    Wc[idx] = (c < 256) ? Wt[(size_t)c * DIN + k] : Wo[(size_t)(c - 256) * DIN + k];
  } else {
    int c = (b - 256) * 256 + tid;
    if (c < 384) bc[c] = (c < 256) ? bt[c] : bo[c - 256];
  }
}

// ---------------- K2: GEMM blocks (BN finalize inlined) ------------------
// 512 blocks, 16 rows each: Hxh(bf16) / HW / sq.
__global__ __launch_bounds__(256) void k_rows(
    const float* __restrict__ H,
    const float* __restrict__ part_s, const float* __restrict__ part_s2,
    const float* __restrict__ gamma, const float* __restrict__ beta,
    const float* __restrict__ Wc, const float* __restrict__ bc,
    unsigned short* __restrict__ Hxh, float* __restrict__ HW,
    float* __restrict__ sq) {
  int tid = threadIdx.x;
  int b = blockIdx.x;
  __shared__ __align__(16) float ssc[DIN];
  __shared__ __align__(16) float ssh[DIN];
  __shared__ float hn[16][DIN];   // 8 KB; reads below are wave-broadcast
  // inline BN finalize (identical bit-exact result in every block)
  if (tid < DIN) {
    float s = 0.f, s2 = 0.f;
    for (int g = 0; g < 64; ++g) { s += part_s[g*DIN+tid]; s2 += part_s2[g*DIN+tid]; }
    float mean = s * (1.0f / N);
    float var  = s2 * (1.0f / N) - mean * mean;
    float sc = rsqrtf(var + 1e-5f) * gamma[tid];
    ssc[tid] = sc;
    ssh[tid] = beta[tid] - mean * sc;
  }
  __syncthreads();
  int base = b * 16;
#pragma unroll
  for (int k = 0; k < 2; ++k) {
    int f = tid + k * 256;
    int r = f >> 5, c4 = f & 31;
    float4 h  = ((const float4*)(H + (size_t)(base + r) * DIN))[c4];
    float4 sc = ((const float4*)ssc)[c4];
    float4 sh = ((const float4*)ssh)[c4];
    h.x = h.x * sc.x + sh.x; h.y = h.y * sc.y + sh.y;
    h.z = h.z * sc.z + sh.z; h.w = h.w * sc.w + sh.w;
    ((float4*)hn[r])[c4] = h;
  }
  __syncthreads();
  int w = tid >> 6, lane = tid & 63;
  int r0 = w * 4;
  float acc[4][6];
#pragma unroll
  for (int r = 0; r < 4; ++r)
#pragma unroll
    for (int q = 0; q < 6; ++q) acc[r][q] = 0.f;

  for (int k4 = 0; k4 < 32; ++k4) {
    float4 h[4];
#pragma unroll
    for (int r = 0; r < 4; ++r) h[r] = ((const float4*)hn[r0 + r])[k4];
#pragma unroll
    for (int kk = 0; kk < 4; ++kk) {
      const float* wrow = Wc + (size_t)(k4 * 4 + kk) * 384 + lane;
      float wv[6];
#pragma unroll
      for (int q = 0; q < 6; ++q) wv[q] = wrow[64 * q];
#pragma unroll
      for (int r = 0; r < 4; ++r) {
        float hs = (kk == 0) ? h[r].x : (kk == 1) ? h[r].y
                 : (kk == 2) ? h[r].z : h[r].w;
#pragma unroll
        for (int q = 0; q < 6; ++q) acc[r][q] += hs * wv[q];
      }
    }
  }
#pragma unroll
  for (int r = 0; r < 4; ++r) {
    int row = base + r0 + r;
    float s = 0.f;
#pragma unroll
    for (int q = 0; q < 4; ++q) {
      float v = acc[r][q] + bc[lane + 64 * q];
      Hxh[(size_t)row * DTH + lane + 64 * q] = f2bf(v);
      s += v * v;
    }
#pragma unroll
    for (int off = 32; off > 0; off >>= 1) s += __shfl_xor(s, off, 64);
    if (lane == 0) sq[row] = s;
#pragma unroll
    for (int q = 4; q < 6; ++q) {
      float v = acc[r][q] + bc[lane + 64 * q];
      HW[(size_t)row * DOUT + lane + 64 * (q - 4)] = v;
    }
  }
}

// ---------------- K3: full-row dense pass, no atomics, no zero-pass ------
// Each block owns one A3 row. dist is symmetric and the DropEdge keep bit
// is keyed on min(i,j)*N+max(i,j), so the row is computable locally —
// both triangles. Row is assembled in a 32 KB LDS buffer, then streamed
// out with nontemporal float4 stores. deg[i] / nnz lists are per-row.
__global__ __launch_bounds__(256) void k_main(
    const float* __restrict__ A_adj, const unsigned short* __restrict__ Hxh,
    const float* __restrict__ sq, float* __restrict__ A3,
    float* __restrict__ deg, int* __restrict__ nnz_cnt,
    int* __restrict__ nnz_idx, float* __restrict__ nnz_val) {
  int i = blockIdx.x;
  int tid = threadIdx.x;
  __shared__ __align__(16) float rowbuf[N];   // 32 KB dense row
  __shared__ float4 hx4[64];                  // hx_i as 64 float4 (f32)
  __shared__ int   s_list[LISTCAP];
  __shared__ int   s_kidx[ROWCAP];
  __shared__ float s_kval[ROWCAP];
  __shared__ int   s_cnt;
  __shared__ int   s_keep;
  __shared__ float s_degp[4];
  if (tid == 0) { s_cnt = 0; s_keep = 0; }

  vfloat4* rb4 = (vfloat4*)rowbuf;
  const vfloat4 z = {0.f, 0.f, 0.f, 0.f};
#pragma unroll
  for (int it = 0; it < 8; ++it) rb4[tid + it * 256] = z;
  ((float*)hx4)[tid] = __uint_as_float(((uint32_t)Hxh[(size_t)i * DTH + tid]) << 16);
  __syncthreads();

  // -- scan full A_adj row, collect candidate columns --
  const vfloat4* arow = (const vfloat4*)(A_adj + (size_t)i * N);
  vfloat4 av8[8];
#pragma unroll
  for (int it = 0; it < 8; ++it)
    av8[it] = __builtin_nontemporal_load(arow + tid + it * 256);
#pragma unroll
  for (int it = 0; it < 8; ++it) {
    int jb = (tid + it * 256) * 4;
    float av[4] = {av8[it].x, av8[it].y, av8[it].z, av8[it].w};
#pragma unroll
    for (int q = 0; q < 4; ++q) {
      if (av[q] != 0.f) {
        int p = atomicAdd(&s_cnt, 1);
        if (p < LISTCAP) s_list[p] = jb + q;
      }
    }
  }
  __syncthreads();

  // -- compute values for candidates, scatter into LDS row --
  int M = min(s_cnt, LISTCAP);
  float sqi = sq[i];
  float dpart = 0.f;
  for (int t = tid; t < M; t += 256) {
    int j = s_list[t];
    float dist;
    if (j == i) {
      dist = 1e-6f;                      // exact diagonal: sqrt(clip(0,1e-12))
    } else {
      const uint4* hj = (const uint4*)(Hxh + (size_t)j * DTH);
      float dot = 0.f;
#pragma unroll 8
      for (int c = 0; c < 32; ++c) {
        uint4 u = hj[c];
        float4 f0 = hx4[2 * c], f1 = hx4[2 * c + 1];
        dot += __uint_as_float(u.x << 16) * f0.x
             + __uint_as_float(u.x & 0xffff0000u) * f0.y
             + __uint_as_float(u.y << 16) * f0.z
             + __uint_as_float(u.y & 0xffff0000u) * f0.w
             + __uint_as_float(u.z << 16) * f1.x
             + __uint_as_float(u.z & 0xffff0000u) * f1.y
             + __uint_as_float(u.w << 16) * f1.z
             + __uint_as_float(u.w & 0xffff0000u) * f1.w;
      }
      dist = sqrtf(fmaxf(sqi + sq[j] - 2.0f * dot, 1e-12f));
    }
    uint32_t uu = (uint32_t)min(i, j), vv = (uint32_t)max(i, j);
    bool keep = dropedge_keep(uu * (uint32_t)N + vv);
    float aval = expf(-0.2f * dist);
    float sg = fmaxf(1.0f / (1.0f + expf(-aval)), 0.1f);
    float bb = keep ? sg : 0.0f;
    float a2 = bb + ((i == j) ? 1.0f : 0.0f);
    float a3v = (a2 > 0.6f) ? a2 : 0.0f;
    if (a3v != 0.f) {
      rowbuf[j] = a3v;
      dpart += a3v;
      int p = atomicAdd(&s_keep, 1);
      if (p < ROWCAP) { s_kidx[p] = j; s_kval[p] = a3v; }
    }
  }
  // block reduction for deg[i]
#pragma unroll
  for (int off = 32; off > 0; off >>= 1) dpart += __shfl_xor(dpart, off, 64);
  int w = tid >> 6, lane = tid & 63;
  if (lane == 0) s_degp[w] = dpart;
  __syncthreads();

  // -- stream dense row out --
  vfloat4* orow = (vfloat4*)(A3 + (size_t)i * N);
#pragma unroll
  for (int it = 0; it < 8; ++it)
    __builtin_nontemporal_store(rb4[tid + it * 256], orow + tid + it * 256);

  int K = min(s_keep, ROWCAP);
  if (tid == 0) {
    deg[i] = s_degp[0] + s_degp[1] + s_degp[2] + s_degp[3];
    nnz_cnt[i] = K;
  }
  for (int t = tid; t < K; t += 256) {
    nnz_idx[(size_t)i * ROWCAP + t] = s_kidx[t];
    nnz_val[(size_t)i * ROWCAP + t] = s_kval[t];
  }
}

// ---------------- K4: out = lrelu(D^-1/2 A3 D^-1/2 @ HW) -----------------
__global__ __launch_bounds__(128) void k_post(
    const float* __restrict__ HW, const float* __restrict__ deg,
    const int* __restrict__ nnz_cnt, const int* __restrict__ nnz_idx,
    const float* __restrict__ nnz_val, float* __restrict__ out) {
  int i = blockIdx.x;
  int c = threadIdx.x;      // 128
  int cnt = min(nnz_cnt[i], ROWCAP);
  float acc = 0.f;
  for (int e = 0; e < cnt; ++e) {
    int j = nnz_idx[(size_t)i * ROWCAP + e];
    float v = nnz_val[(size_t)i * ROWCAP + e];
    acc += v * rsqrtf(deg[j]) * HW[(size_t)j * DOUT + c];
  }
  float o = rsqrtf(deg[i]) * acc;
  out[(size_t)i * DOUT + c] = (o >= 0.f) ? o : 0.01f * o;
}

// ---------------- launch --------------------------------------------------
extern "C" void kernel_launch(void* const* d_in, const int* in_sizes, int n_in,
                              void* d_out, int out_size, void* d_ws, size_t ws_size,
                              hipStream_t stream) {
  const float* H     = (const float*)d_in[0];
  const float* A_adj = (const float*)d_in[1];
  const float* gamma = (const float*)d_in[2];
  const float* beta  = (const float*)d_in[3];
  const float* Wt    = (const float*)d_in[4];
  const float* bt    = (const float*)d_in[5];
  const float* Wo    = (const float*)d_in[6];
  const float* bo    = (const float*)d_in[7];

  float* out = (float*)d_out;                    // [N, DOUT]
  float* A3  = out + (size_t)N * DOUT;           // [N, N]

  float* ws    = (float*)d_ws;
  unsigned short* Hxh = (unsigned short*)ws;      // N*256 bf16 (= N*128 floats)
  float* sq    = ws + (size_t)N * 128;            // N
  float* HW    = sq + N;                          // N*128
  float* deg   = HW + (size_t)N * DOUT;           // N
  int*   nnz_cnt = (int*)(deg + N);               // N
  int*   nnz_idx = nnz_cnt + N;                   // N*ROWCAP
  float* nnz_val = (float*)(nnz_idx + (size_t)N * ROWCAP); // N*ROWCAP
  float* part_s  = nnz_val + (size_t)N * ROWCAP;  // 64*128
  float* part_s2 = part_s + 64 * DIN;             // 64*128
  float* Wc      = part_s2 + 64 * DIN;            // 128*384
  float* bc      = Wc + 128 * 384;                // 384

  k_pre<<<258, 256, 0, stream>>>(H, Wt, bt, Wo, bo, part_s, part_s2, Wc, bc);
  k_rows<<<512, 256, 0, stream>>>(H, part_s, part_s2, gamma, beta, Wc, bc,
                                  Hxh, HW, sq);
  k_main<<<N, 256, 0, stream>>>(A_adj, Hxh, sq, A3, deg, nnz_cnt, nnz_idx, nnz_val);
  k_post<<<N, DOUT, 0, stream>>>(HW, deg, nnz_cnt, nnz_idx, nnz_val, out);
}

// Round 2
// 484.951 us; speedup vs baseline: 1.0433x; 1.0433x over previous
//
#include <hip/hip_runtime.h>
#include <cstdint>
#include <cstddef>

#define N 8192
#define DIN 128
#define DTH 256
#define DOUT 128
#define ROWCAP 256
#define LISTCAP 256

typedef float vfloat4 __attribute__((ext_vector_type(4)));

// ---------------- threefry2x32 with key (0, 42) --------------------------
__device__ __forceinline__ void threefry_0_42(uint32_t x0, uint32_t x1,
                                              uint32_t& o0, uint32_t& o1) {
  const uint32_t ks0 = 0u;
  const uint32_t ks1 = 42u;
  const uint32_t ks2 = 0x1BD11BDAu ^ 0u ^ 42u;
  x0 += ks0; x1 += ks1;
#define TF_R(r) { x0 += x1; x1 = (x1 << (r)) | (x1 >> (32 - (r))); x1 ^= x0; }
  TF_R(13) TF_R(15) TF_R(26) TF_R(6)
  x0 += ks1; x1 += ks2 + 1u;
  TF_R(17) TF_R(29) TF_R(16) TF_R(24)
  x0 += ks2; x1 += ks0 + 2u;
  TF_R(13) TF_R(15) TF_R(26) TF_R(6)
  x0 += ks0; x1 += ks1 + 3u;
  TF_R(17) TF_R(29) TF_R(16) TF_R(24)
  x0 += ks1; x1 += ks2 + 4u;
  TF_R(13) TF_R(15) TF_R(26) TF_R(6)
  x0 += ks2; x1 += ks0 + 5u;
#undef TF_R
  o0 = x0; o1 = x1;
}

__device__ __forceinline__ bool dropedge_keep(uint32_t t) {
  uint32_t y0, y1;
  threefry_0_42(0u, t, y0, y1);
  uint32_t bits = y0 ^ y1;
  float u = __uint_as_float((bits >> 9) | 0x3f800000u) - 1.0f;
  return u < 0.8f;
}

__device__ __forceinline__ unsigned short f2bf(float v) {
  uint32_t u = __float_as_uint(v);
  u += 0x7fffu + ((u >> 16) & 1u);     // round-to-nearest-even
  return (unsigned short)(u >> 16);
}

// ---------------- K1: fused bn_part + W pack + counter zero --------------
// blocks [0,64): BN partial sums; [64,256): Wc pack; [256,258): bc;
// [258,274): zero deg + nnz_cnt (contiguous 64 KB).
__global__ __launch_bounds__(256) void k_pre(
    const float* __restrict__ H,
    const float* __restrict__ Wt, const float* __restrict__ bt,
    const float* __restrict__ Wo, const float* __restrict__ bo,
    float* __restrict__ part_s, float* __restrict__ part_s2,
    float* __restrict__ Wc, float* __restrict__ bc,
    float* __restrict__ deg /* deg + nnz_cnt contiguous */) {
  int b = blockIdx.x;
  int tid = threadIdx.x;
  if (b < 64) {
    __shared__ float ls[8][DIN];
    __shared__ float ls2[8][DIN];
    int rg = tid >> 5;
    int c4 = tid & 31;
    int rbase = b * 128;
    float s[4] = {0,0,0,0}, s2[4] = {0,0,0,0};
    for (int k = 0; k < 16; ++k) {
      int r = rbase + rg + k * 8;
      float4 h = ((const float4*)(H + (size_t)r * DIN))[c4];
      s[0] += h.x; s2[0] += h.x * h.x;
      s[1] += h.y; s2[1] += h.y * h.y;
      s[2] += h.z; s2[2] += h.z * h.z;
      s[3] += h.w; s2[3] += h.w * h.w;
    }
#pragma unroll
    for (int q = 0; q < 4; ++q) { ls[rg][c4*4+q] = s[q]; ls2[rg][c4*4+q] = s2[q]; }
    __syncthreads();
    if (tid < DIN) {
      float a = 0.f, bb = 0.f;
#pragma unroll
      for (int g = 0; g < 8; ++g) { a += ls[g][tid]; bb += ls2[g][tid]; }
      part_s[b * DIN + tid] = a;
      part_s2[b * DIN + tid] = bb;
    }
  } else if (b < 256) {
    int idx = (b - 64) * 256 + tid;        // [0, 49152)
    int k = idx / 384, c = idx % 384;
    Wc[idx] = (c < 256) ? Wt[(size_t)c * DIN + k] : Wo[(size_t)(c - 256) * DIN + k];
  } else if (b < 258) {
    int c = (b - 256) * 256 + tid;
    if (c < 384) bc[c] = (c < 256) ? bt[c] : bo[c - 256];
  } else {
    int g = (b - 258) * 256 + tid;         // [0, 4096) int4 = 64 KB
    ((int4*)deg)[g] = make_int4(0, 0, 0, 0);
  }
}

// ---------------- K2: GEMM blocks (BN finalize inlined) ------------------
// 512 blocks, 16 rows each: Hxh(bf16) / HW / sq.
__global__ __launch_bounds__(256) void k_rows(
    const float* __restrict__ H,
    const float* __restrict__ part_s, const float* __restrict__ part_s2,
    const float* __restrict__ gamma, const float* __restrict__ beta,
    const float* __restrict__ Wc, const float* __restrict__ bc,
    unsigned short* __restrict__ Hxh, float* __restrict__ HW,
    float* __restrict__ sq) {
  int tid = threadIdx.x;
  int b = blockIdx.x;
  __shared__ __align__(16) float ssc[DIN];
  __shared__ __align__(16) float ssh[DIN];
  __shared__ float hn[16][DIN];   // 8 KB; reads below are wave-broadcast
  // inline BN finalize (identical bit-exact result in every block)
  if (tid < DIN) {
    float s = 0.f, s2 = 0.f;
    for (int g = 0; g < 64; ++g) { s += part_s[g*DIN+tid]; s2 += part_s2[g*DIN+tid]; }
    float mean = s * (1.0f / N);
    float var  = s2 * (1.0f / N) - mean * mean;
    float sc = rsqrtf(var + 1e-5f) * gamma[tid];
    ssc[tid] = sc;
    ssh[tid] = beta[tid] - mean * sc;
  }
  __syncthreads();
  int base = b * 16;
#pragma unroll
  for (int k = 0; k < 2; ++k) {
    int f = tid + k * 256;
    int r = f >> 5, c4 = f & 31;
    float4 h  = ((const float4*)(H + (size_t)(base + r) * DIN))[c4];
    float4 sc = ((const float4*)ssc)[c4];
    float4 sh = ((const float4*)ssh)[c4];
    h.x = h.x * sc.x + sh.x; h.y = h.y * sc.y + sh.y;
    h.z = h.z * sc.z + sh.z; h.w = h.w * sc.w + sh.w;
    ((float4*)hn[r])[c4] = h;
  }
  __syncthreads();
  int w = tid >> 6, lane = tid & 63;
  int r0 = w * 4;
  float acc[4][6];
#pragma unroll
  for (int r = 0; r < 4; ++r)
#pragma unroll
    for (int q = 0; q < 6; ++q) acc[r][q] = 0.f;

  for (int k4 = 0; k4 < 32; ++k4) {
    float4 h[4];
#pragma unroll
    for (int r = 0; r < 4; ++r) h[r] = ((const float4*)hn[r0 + r])[k4];
#pragma unroll
    for (int kk = 0; kk < 4; ++kk) {
      const float* wrow = Wc + (size_t)(k4 * 4 + kk) * 384 + lane;
      float wv[6];
#pragma unroll
      for (int q = 0; q < 6; ++q) wv[q] = wrow[64 * q];
#pragma unroll
      for (int r = 0; r < 4; ++r) {
        float hs = (kk == 0) ? h[r].x : (kk == 1) ? h[r].y
                 : (kk == 2) ? h[r].z : h[r].w;
#pragma unroll
        for (int q = 0; q < 6; ++q) acc[r][q] += hs * wv[q];
      }
    }
  }
#pragma unroll
  for (int r = 0; r < 4; ++r) {
    int row = base + r0 + r;
    float s = 0.f;
#pragma unroll
    for (int q = 0; q < 4; ++q) {
      float v = acc[r][q] + bc[lane + 64 * q];
      Hxh[(size_t)row * DTH + lane + 64 * q] = f2bf(v);
      s += v * v;
    }
#pragma unroll
    for (int off = 32; off > 0; off >>= 1) s += __shfl_xor(s, off, 64);
    if (lane == 0) sq[row] = s;
#pragma unroll
    for (int q = 4; q < 6; ++q) {
      float v = acc[r][q] + bc[lane + 64 * q];
      HW[(size_t)row * DOUT + lane + 64 * (q - 4)] = v;
    }
  }
}

// ---------------- K3a: upper-tri edge pass -> compressed lists only ------
// No A3 traffic at all. Each edge computed once. deg[i] block-reduced to a
// single atomic; mirrored side uses per-edge atomics (different addresses).
// Tiny LDS -> 8 blocks/CU = 32 waves/CU.
__global__ __launch_bounds__(256) void k_edges(
    const float* __restrict__ A_adj, const unsigned short* __restrict__ Hxh,
    const float* __restrict__ sq,
    float* __restrict__ deg, int* __restrict__ nnz_cnt,
    int* __restrict__ nnz_idx, float* __restrict__ nnz_val) {
  int i = blockIdx.x;
  int tid = threadIdx.x;
  __shared__ float4 hx4[64];          // hx_i as 64 float4
  __shared__ int   s_list[LISTCAP];
  __shared__ int   s_cnt;
  __shared__ float s_degp[4];
  if (tid == 0) s_cnt = 0;
  ((float*)hx4)[tid] = __uint_as_float(((uint32_t)Hxh[(size_t)i * DTH + tid]) << 16);
  __syncthreads();

  const vfloat4* arow = (const vfloat4*)(A_adj + (size_t)i * N);
  int q0 = i >> 2;
  for (int q4 = q0 + tid; q4 < N / 4; q4 += 256) {
    vfloat4 a = __builtin_nontemporal_load(arow + q4);
    int jb = q4 * 4;
    float av[4] = {a.x, a.y, a.z, a.w};
#pragma unroll
    for (int q = 0; q < 4; ++q) {
      int j = jb + q;
      if (av[q] != 0.f && j >= i) {
        int p = atomicAdd(&s_cnt, 1);
        if (p < LISTCAP) s_list[p] = j;
      }
    }
  }
  __syncthreads();

  int M = min(s_cnt, LISTCAP);
  float sqi = sq[i];
  float dpart = 0.f;
  for (int t = tid; t < M; t += 256) {
    int j = s_list[t];
    bool keep = dropedge_keep((uint32_t)i * (uint32_t)N + (uint32_t)j);
    float dist;
    if (j == i) {
      dist = 1e-6f;                      // exact diagonal: sqrt(clip(0,1e-12))
    } else {
      const uint4* hj = (const uint4*)(Hxh + (size_t)j * DTH);
      float dot = 0.f;
#pragma unroll 8
      for (int c = 0; c < 32; ++c) {
        uint4 u = hj[c];
        float4 f0 = hx4[2 * c], f1 = hx4[2 * c + 1];
        dot += __uint_as_float(u.x << 16) * f0.x
             + __uint_as_float(u.x & 0xffff0000u) * f0.y
             + __uint_as_float(u.y << 16) * f0.z
             + __uint_as_float(u.y & 0xffff0000u) * f0.w
             + __uint_as_float(u.z << 16) * f1.x
             + __uint_as_float(u.z & 0xffff0000u) * f1.y
             + __uint_as_float(u.w << 16) * f1.z
             + __uint_as_float(u.w & 0xffff0000u) * f1.w;
      }
      dist = sqrtf(fmaxf(sqi + sq[j] - 2.0f * dot, 1e-12f));
    }
    float aval = expf(-0.2f * dist);
    float sg = fmaxf(1.0f / (1.0f + expf(-aval)), 0.1f);
    float bb = keep ? sg : 0.0f;
    float a2 = bb + ((i == j) ? 1.0f : 0.0f);
    float a3v = (a2 > 0.6f) ? a2 : 0.0f;
    if (a3v != 0.f) {
      dpart += a3v;                      // deg[i] contribution, reduced below
      int p = atomicAdd(&nnz_cnt[i], 1);
      if (p < ROWCAP) {
        nnz_idx[(size_t)i * ROWCAP + p] = j;
        nnz_val[(size_t)i * ROWCAP + p] = a3v;
      }
      if (j != i) {
        atomicAdd(&deg[j], a3v);
        int p2 = atomicAdd(&nnz_cnt[j], 1);
        if (p2 < ROWCAP) {
          nnz_idx[(size_t)j * ROWCAP + p2] = i;
          nnz_val[(size_t)j * ROWCAP + p2] = a3v;
        }
      }
    }
  }
  // block reduction for deg[i] (one atomic per block instead of ~33)
#pragma unroll
  for (int off = 32; off > 0; off >>= 1) dpart += __shfl_xor(dpart, off, 64);
  int w = tid >> 6, lane = tid & 63;
  if (lane == 0) s_degp[w] = dpart;
  __syncthreads();
  if (tid == 0) {
    float d = s_degp[0] + s_degp[1] + s_degp[2] + s_degp[3];
    if (d != 0.f) atomicAdd(&deg[i], d);
  }
}

// ---------------- K3b: dense A3 materialization + fused out --------------
// 1024-thread blocks, one row each. Build row in 32 KB LDS from the
// compressed list, stream out with nt float4 stores. Tail fuses the old
// k_post: 8 column-groups accumulate the sparse SpMM from the LDS list.
// LDS ~38 KB -> 2 blocks/CU = 32 waves/CU (full occupancy).
__global__ __launch_bounds__(1024) void k_mat(
    const float* __restrict__ HW, const float* __restrict__ deg,
    const int* __restrict__ nnz_cnt, const int* __restrict__ nnz_idx,
    const float* __restrict__ nnz_val,
    float* __restrict__ A3, float* __restrict__ out) {
  int i = blockIdx.x;
  int tid = threadIdx.x;
  __shared__ __align__(16) float rowbuf[N];    // 32 KB
  __shared__ int   s_idx[ROWCAP];
  __shared__ float s_val[ROWCAP];
  __shared__ float pacc[8][DOUT];              // 4 KB

  vfloat4* rb4 = (vfloat4*)rowbuf;
  const vfloat4 z = {0.f, 0.f, 0.f, 0.f};
  rb4[tid] = z;
  rb4[tid + 1024] = z;

  int cnt = min(nnz_cnt[i], ROWCAP);
  if (tid < cnt) {
    s_idx[tid] = nnz_idx[(size_t)i * ROWCAP + tid];
    s_val[tid] = nnz_val[(size_t)i * ROWCAP + tid];
  }
  __syncthreads();
  if (tid < cnt) rowbuf[s_idx[tid]] = s_val[tid];
  __syncthreads();

  vfloat4* orow = (vfloat4*)(A3 + (size_t)i * N);
  __builtin_nontemporal_store(rb4[tid], orow + tid);
  __builtin_nontemporal_store(rb4[tid + 1024], orow + tid + 1024);

  // fused k_post: out[i,:] = lrelu(rsqrt(deg_i) * sum_e v_e rsqrt(deg_j) HW[j,:])
  int c = tid & 127, g = tid >> 7;             // 8 groups x 128 cols
  float acc = 0.f;
  for (int e = g; e < cnt; e += 8)
    acc += s_val[e] * rsqrtf(deg[s_idx[e]]) * HW[(size_t)s_idx[e] * DOUT + c];
  pacc[g][c] = acc;
  __syncthreads();
  if (tid < DOUT) {
    float a = 0.f;
#pragma unroll
    for (int gg = 0; gg < 8; ++gg) a += pacc[gg][tid];
    float o = rsqrtf(deg[i]) * a;
    out[(size_t)i * DOUT + tid] = (o >= 0.f) ? o : 0.01f * o;
  }
}

// ---------------- launch --------------------------------------------------
extern "C" void kernel_launch(void* const* d_in, const int* in_sizes, int n_in,
                              void* d_out, int out_size, void* d_ws, size_t ws_size,
                              hipStream_t stream) {
  const float* H     = (const float*)d_in[0];
  const float* A_adj = (const float*)d_in[1];
  const float* gamma = (const float*)d_in[2];
  const float* beta  = (const float*)d_in[3];
  const float* Wt    = (const float*)d_in[4];
  const float* bt    = (const float*)d_in[5];
  const float* Wo    = (const float*)d_in[6];
  const float* bo    = (const float*)d_in[7];

  float* out = (float*)d_out;                    // [N, DOUT]
  float* A3  = out + (size_t)N * DOUT;           // [N, N]

  float* ws    = (float*)d_ws;
  unsigned short* Hxh = (unsigned short*)ws;      // N*256 bf16 (= N*128 floats)
  float* sq    = ws + (size_t)N * 128;            // N
  float* HW    = sq + N;                          // N*128
  float* deg   = HW + (size_t)N * DOUT;           // N   (deg+cnt contiguous!)
  int*   nnz_cnt = (int*)(deg + N);               // N
  int*   nnz_idx = nnz_cnt + N;                   // N*ROWCAP
  float* nnz_val = (float*)(nnz_idx + (size_t)N * ROWCAP); // N*ROWCAP
  float* part_s  = nnz_val + (size_t)N * ROWCAP;  // 64*128
  float* part_s2 = part_s + 64 * DIN;             // 64*128
  float* Wc      = part_s2 + 64 * DIN;            // 128*384
  float* bc      = Wc + 128 * 384;                // 384

  k_pre<<<274, 256, 0, stream>>>(H, Wt, bt, Wo, bo, part_s, part_s2, Wc, bc, deg);
  k_rows<<<512, 256, 0, stream>>>(H, part_s, part_s2, gamma, beta, Wc, bc,
                                  Hxh, HW, sq);
  k_edges<<<N, 256, 0, stream>>>(A_adj, Hxh, sq, deg, nnz_cnt, nnz_idx, nnz_val);
  k_mat<<<N, 1024, 0, stream>>>(HW, deg, nnz_cnt, nnz_idx, nnz_val, A3, out);
}

// Round 3
// 481.021 us; speedup vs baseline: 1.0519x; 1.0082x over previous
//
#include <hip/hip_runtime.h>
#include <cstdint>
#include <cstddef>

#define N 8192
#define DIN 128
#define DTH 256
#define DOUT 128
#define ROWCAP 256
#define LISTCAP 256

typedef float vfloat4 __attribute__((ext_vector_type(4)));

// ---------------- threefry2x32 with key (0, 42) --------------------------
__device__ __forceinline__ void threefry_0_42(uint32_t x0, uint32_t x1,
                                              uint32_t& o0, uint32_t& o1) {
  const uint32_t ks0 = 0u;
  const uint32_t ks1 = 42u;
  const uint32_t ks2 = 0x1BD11BDAu ^ 0u ^ 42u;
  x0 += ks0; x1 += ks1;
#define TF_R(r) { x0 += x1; x1 = (x1 << (r)) | (x1 >> (32 - (r))); x1 ^= x0; }
  TF_R(13) TF_R(15) TF_R(26) TF_R(6)
  x0 += ks1; x1 += ks2 + 1u;
  TF_R(17) TF_R(29) TF_R(16) TF_R(24)
  x0 += ks2; x1 += ks0 + 2u;
  TF_R(13) TF_R(15) TF_R(26) TF_R(6)
  x0 += ks0; x1 += ks1 + 3u;
  TF_R(17) TF_R(29) TF_R(16) TF_R(24)
  x0 += ks1; x1 += ks2 + 4u;
  TF_R(13) TF_R(15) TF_R(26) TF_R(6)
  x0 += ks2; x1 += ks0 + 5u;
#undef TF_R
  o0 = x0; o1 = x1;
}

__device__ __forceinline__ bool dropedge_keep(uint32_t t) {
  uint32_t y0, y1;
  threefry_0_42(0u, t, y0, y1);
  uint32_t bits = y0 ^ y1;
  float u = __uint_as_float((bits >> 9) | 0x3f800000u) - 1.0f;
  return u < 0.8f;
}

__device__ __forceinline__ unsigned short f2bf(float v) {
  uint32_t u = __float_as_uint(v);
  u += 0x7fffu + ((u >> 16) & 1u);     // round-to-nearest-even
  return (unsigned short)(u >> 16);
}

// ---------------- K1: fused bn_part + W pack + counter zero --------------
// blocks [0,64): BN partial sums; [64,256): Wc pack; [256,258): bc;
// [258,274): zero deg + nnz_cnt (contiguous 64 KB).
__global__ __launch_bounds__(256) void k_pre(
    const float* __restrict__ H,
    const float* __restrict__ Wt, const float* __restrict__ bt,
    const float* __restrict__ Wo, const float* __restrict__ bo,
    float* __restrict__ part_s, float* __restrict__ part_s2,
    float* __restrict__ Wc, float* __restrict__ bc,
    float* __restrict__ deg /* deg + nnz_cnt contiguous */) {
  int b = blockIdx.x;
  int tid = threadIdx.x;
  if (b < 64) {
    __shared__ float ls[8][DIN];
    __shared__ float ls2[8][DIN];
    int rg = tid >> 5;
    int c4 = tid & 31;
    int rbase = b * 128;
    float s[4] = {0,0,0,0}, s2[4] = {0,0,0,0};
    for (int k = 0; k < 16; ++k) {
      int r = rbase + rg + k * 8;
      float4 h = ((const float4*)(H + (size_t)r * DIN))[c4];
      s[0] += h.x; s2[0] += h.x * h.x;
      s[1] += h.y; s2[1] += h.y * h.y;
      s[2] += h.z; s2[2] += h.z * h.z;
      s[3] += h.w; s2[3] += h.w * h.w;
    }
#pragma unroll
    for (int q = 0; q < 4; ++q) { ls[rg][c4*4+q] = s[q]; ls2[rg][c4*4+q] = s2[q]; }
    __syncthreads();
    if (tid < DIN) {
      float a = 0.f, bb = 0.f;
#pragma unroll
      for (int g = 0; g < 8; ++g) { a += ls[g][tid]; bb += ls2[g][tid]; }
      part_s[b * DIN + tid] = a;
      part_s2[b * DIN + tid] = bb;
    }
  } else if (b < 256) {
    int idx = (b - 64) * 256 + tid;        // [0, 49152)
    int k = idx / 384, c = idx % 384;
    Wc[idx] = (c < 256) ? Wt[(size_t)c * DIN + k] : Wo[(size_t)(c - 256) * DIN + k];
  } else if (b < 258) {
    int c = (b - 256) * 256 + tid;
    if (c < 384) bc[c] = (c < 256) ? bt[c] : bo[c - 256];
  } else {
    int g = (b - 258) * 256 + tid;         // [0, 4096) int4 = 64 KB
    ((int4*)deg)[g] = make_int4(0, 0, 0, 0);
  }
}

// ---------------- K2: pure GEMM, 512 blocks (BN finalize inlined) --------
__global__ __launch_bounds__(256) void k_rows(
    const float* __restrict__ H,
    const float* __restrict__ part_s, const float* __restrict__ part_s2,
    const float* __restrict__ gamma, const float* __restrict__ beta,
    const float* __restrict__ Wc, const float* __restrict__ bc,
    unsigned short* __restrict__ Hxh, float* __restrict__ HW,
    float* __restrict__ sq) {
  int tid = threadIdx.x;
  int b = blockIdx.x;
  __shared__ __align__(16) float ssc[DIN];
  __shared__ __align__(16) float ssh[DIN];
  __shared__ float hn[16][DIN];   // 8 KB; reads below are wave-broadcast
  // inline BN finalize (identical bit-exact result in every block)
  if (tid < DIN) {
    float s = 0.f, s2 = 0.f;
    for (int g = 0; g < 64; ++g) { s += part_s[g*DIN+tid]; s2 += part_s2[g*DIN+tid]; }
    float mean = s * (1.0f / N);
    float var  = s2 * (1.0f / N) - mean * mean;
    float sc = rsqrtf(var + 1e-5f) * gamma[tid];
    ssc[tid] = sc;
    ssh[tid] = beta[tid] - mean * sc;
  }
  __syncthreads();
  int base = b * 16;
#pragma unroll
  for (int k = 0; k < 2; ++k) {
    int f = tid + k * 256;
    int r = f >> 5, c4 = f & 31;
    float4 h  = ((const float4*)(H + (size_t)(base + r) * DIN))[c4];
    float4 sc = ((const float4*)ssc)[c4];
    float4 sh = ((const float4*)ssh)[c4];
    h.x = h.x * sc.x + sh.x; h.y = h.y * sc.y + sh.y;
    h.z = h.z * sc.z + sh.z; h.w = h.w * sc.w + sh.w;
    ((float4*)hn[r])[c4] = h;
  }
  __syncthreads();
  int w = tid >> 6, lane = tid & 63;
  int r0 = w * 4;
  float acc[4][6];
#pragma unroll
  for (int r = 0; r < 4; ++r)
#pragma unroll
    for (int q = 0; q < 6; ++q) acc[r][q] = 0.f;

  for (int k4 = 0; k4 < 32; ++k4) {
    float4 h[4];
#pragma unroll
    for (int r = 0; r < 4; ++r) h[r] = ((const float4*)hn[r0 + r])[k4];
#pragma unroll
    for (int kk = 0; kk < 4; ++kk) {
      const float* wrow = Wc + (size_t)(k4 * 4 + kk) * 384 + lane;
      float wv[6];
#pragma unroll
      for (int q = 0; q < 6; ++q) wv[q] = wrow[64 * q];
#pragma unroll
      for (int r = 0; r < 4; ++r) {
        float hs = (kk == 0) ? h[r].x : (kk == 1) ? h[r].y
                 : (kk == 2) ? h[r].z : h[r].w;
#pragma unroll
        for (int q = 0; q < 6; ++q) acc[r][q] += hs * wv[q];
      }
    }
  }
#pragma unroll
  for (int r = 0; r < 4; ++r) {
    int row = base + r0 + r;
    float s = 0.f;
#pragma unroll
    for (int q = 0; q < 4; ++q) {
      float v = acc[r][q] + bc[lane + 64 * q];
      Hxh[(size_t)row * DTH + lane + 64 * q] = f2bf(v);
      s += v * v;
    }
#pragma unroll
    for (int off = 32; off > 0; off >>= 1) s += __shfl_xor(s, off, 64);
    if (lane == 0) sq[row] = s;
#pragma unroll
    for (int q = 4; q < 6; ++q) {
      float v = acc[r][q] + bc[lane + 64 * q];
      HW[(size_t)row * DOUT + lane + 64 * (q - 4)] = v;
    }
  }
}

// ---------------- K3: fused zero-row + upper-tri edge pass ---------------
// Block i: nt-zero its own A3 row (drained by the first barrier), scan the
// A_adj upper triangle while those writes are in flight, then write its
// own-row survivors directly (same block -> ordered after the zeros).
// Mirror entries A3[j][i] (j>i) would race with block j's zero, so they
// travel via the nnz lists and are stored by k_post.
__global__ __launch_bounds__(256) void k_main(
    const float* __restrict__ A_adj, const unsigned short* __restrict__ Hxh,
    const float* __restrict__ sq, float* __restrict__ A3,
    float* __restrict__ deg, int* __restrict__ nnz_cnt,
    int* __restrict__ nnz_idx, float* __restrict__ nnz_val) {
  int i = blockIdx.x;
  int tid = threadIdx.x;
  __shared__ float4 hx4[64];          // hx_i as 64 float4
  __shared__ int   s_list[LISTCAP];
  __shared__ int   s_cnt;
  __shared__ float s_degp[4];
  if (tid == 0) s_cnt = 0;

  // zero own row (32 KB, nontemporal)
  vfloat4* orow = (vfloat4*)(A3 + (size_t)i * N);
  const vfloat4 z = {0.f, 0.f, 0.f, 0.f};
#pragma unroll
  for (int it = 0; it < 8; ++it)
    __builtin_nontemporal_store(z, orow + tid + it * 256);

  ((float*)hx4)[tid] = __uint_as_float(((uint32_t)Hxh[(size_t)i * DTH + tid]) << 16);
  __syncthreads();    // compiler drains vmcnt before s_barrier: zeros committed

  const vfloat4* arow = (const vfloat4*)(A_adj + (size_t)i * N);
  int q0 = i >> 2;
  for (int q4 = q0 + tid; q4 < N / 4; q4 += 256) {
    vfloat4 a = __builtin_nontemporal_load(arow + q4);
    int jb = q4 * 4;
    float av[4] = {a.x, a.y, a.z, a.w};
#pragma unroll
    for (int q = 0; q < 4; ++q) {
      int j = jb + q;
      if (av[q] != 0.f && j >= i) {
        int p = atomicAdd(&s_cnt, 1);
        if (p < LISTCAP) s_list[p] = j;
      }
    }
  }
  __syncthreads();

  int M = min(s_cnt, LISTCAP);
  float sqi = sq[i];
  float dpart = 0.f;
  for (int t = tid; t < M; t += 256) {
    int j = s_list[t];
    bool keep = dropedge_keep((uint32_t)i * (uint32_t)N + (uint32_t)j);
    float dist;
    if (j == i) {
      dist = 1e-6f;                      // exact diagonal: sqrt(clip(0,1e-12))
    } else {
      const uint4* hj = (const uint4*)(Hxh + (size_t)j * DTH);
      float dot = 0.f;
#pragma unroll 8
      for (int c = 0; c < 32; ++c) {
        uint4 u = hj[c];
        float4 f0 = hx4[2 * c], f1 = hx4[2 * c + 1];
        dot += __uint_as_float(u.x << 16) * f0.x
             + __uint_as_float(u.x & 0xffff0000u) * f0.y
             + __uint_as_float(u.y << 16) * f0.z
             + __uint_as_float(u.y & 0xffff0000u) * f0.w
             + __uint_as_float(u.z << 16) * f1.x
             + __uint_as_float(u.z & 0xffff0000u) * f1.y
             + __uint_as_float(u.w << 16) * f1.z
             + __uint_as_float(u.w & 0xffff0000u) * f1.w;
      }
      dist = sqrtf(fmaxf(sqi + sq[j] - 2.0f * dot, 1e-12f));
    }
    float aval = expf(-0.2f * dist);
    float sg = fmaxf(1.0f / (1.0f + expf(-aval)), 0.1f);
    float bb = keep ? sg : 0.0f;
    float a2 = bb + ((i == j) ? 1.0f : 0.0f);
    float a3v = (a2 > 0.6f) ? a2 : 0.0f;
    if (a3v != 0.f) {
      A3[(size_t)i * N + j] = a3v;       // own row: ordered after the zeros
      dpart += a3v;
      int p = atomicAdd(&nnz_cnt[i], 1);
      if (p < ROWCAP) {
        nnz_idx[(size_t)i * ROWCAP + p] = j;
        nnz_val[(size_t)i * ROWCAP + p] = a3v;
      }
      if (j != i) {
        atomicAdd(&deg[j], a3v);
        int p2 = atomicAdd(&nnz_cnt[j], 1);
        if (p2 < ROWCAP) {
          nnz_idx[(size_t)j * ROWCAP + p2] = i;   // mirror: stored by k_post
          nnz_val[(size_t)j * ROWCAP + p2] = a3v;
        }
      }
    }
  }
  // block reduction for deg[i] (one atomic per block)
#pragma unroll
  for (int off = 32; off > 0; off >>= 1) dpart += __shfl_xor(dpart, off, 64);
  int w = tid >> 6, lane = tid & 63;
  if (lane == 0) s_degp[w] = dpart;
  __syncthreads();
  if (tid == 0) {
    float d = s_degp[0] + s_degp[1] + s_degp[2] + s_degp[3];
    if (d != 0.f) atomicAdd(&deg[i], d);
  }
}

// ---------------- K4: SpMM + mirror A3 stores, 4 rows/block --------------
// Runs after all of k_main: every A3 row is zeroed+upper-written, so the
// sparse mirror stores (j < i entries of row i's list) are race-free.
__global__ __launch_bounds__(256) void k_post(
    const float* __restrict__ HW, const float* __restrict__ deg,
    const int* __restrict__ nnz_cnt, const int* __restrict__ nnz_idx,
    const float* __restrict__ nnz_val,
    float* __restrict__ A3, float* __restrict__ out) {
  int g = threadIdx.x >> 7;       // 0/1: two rows concurrently
  int c = threadIdx.x & 127;
#pragma unroll
  for (int k = 0; k < 2; ++k) {
    int i = blockIdx.x * 4 + g * 2 + k;
    int cnt = min(nnz_cnt[i], ROWCAP);
    float acc = 0.f;
    for (int e = 0; e < cnt; ++e) {
      int j = nnz_idx[(size_t)i * ROWCAP + e];
      float v = nnz_val[(size_t)i * ROWCAP + e];
      if (c == 0 && j < i) A3[(size_t)i * N + j] = v;   // mirror store
      acc += v * rsqrtf(deg[j]) * HW[(size_t)j * DOUT + c];
    }
    float o = rsqrtf(deg[i]) * acc;
    out[(size_t)i * DOUT + c] = (o >= 0.f) ? o : 0.01f * o;
  }
}

// ---------------- launch --------------------------------------------------
extern "C" void kernel_launch(void* const* d_in, const int* in_sizes, int n_in,
                              void* d_out, int out_size, void* d_ws, size_t ws_size,
                              hipStream_t stream) {
  const float* H     = (const float*)d_in[0];
  const float* A_adj = (const float*)d_in[1];
  const float* gamma = (const float*)d_in[2];
  const float* beta  = (const float*)d_in[3];
  const float* Wt    = (const float*)d_in[4];
  const float* bt    = (const float*)d_in[5];
  const float* Wo    = (const float*)d_in[6];
  const float* bo    = (const float*)d_in[7];

  float* out = (float*)d_out;                    // [N, DOUT]
  float* A3  = out + (size_t)N * DOUT;           // [N, N]

  float* ws    = (float*)d_ws;
  unsigned short* Hxh = (unsigned short*)ws;      // N*256 bf16 (= N*128 floats)
  float* sq    = ws + (size_t)N * 128;            // N
  float* HW    = sq + N;                          // N*128
  float* deg   = HW + (size_t)N * DOUT;           // N   (deg+cnt contiguous!)
  int*   nnz_cnt = (int*)(deg + N);               // N
  int*   nnz_idx = nnz_cnt + N;                   // N*ROWCAP
  float* nnz_val = (float*)(nnz_idx + (size_t)N * ROWCAP); // N*ROWCAP
  float* part_s  = nnz_val + (size_t)N * ROWCAP;  // 64*128
  float* part_s2 = part_s + 64 * DIN;             // 64*128
  float* Wc      = part_s2 + 64 * DIN;            // 128*384
  float* bc      = Wc + 128 * 384;                // 384

  k_pre<<<274, 256, 0, stream>>>(H, Wt, bt, Wo, bo, part_s, part_s2, Wc, bc, deg);
  k_rows<<<512, 256, 0, stream>>>(H, part_s, part_s2, gamma, beta, Wc, bc,
                                  Hxh, HW, sq);
  k_main<<<N, 256, 0, stream>>>(A_adj, Hxh, sq, A3, deg, nnz_cnt, nnz_idx, nnz_val);
  k_post<<<N / 4, 256, 0, stream>>>(HW, deg, nnz_cnt, nnz_idx, nnz_val, A3, out);
}

// Round 4
// 477.633 us; speedup vs baseline: 1.0593x; 1.0071x over previous
//
#include <hip/hip_runtime.h>
#include <cstdint>
#include <cstddef>

#define N 8192
#define DIN 128
#define DTH 256
#define DOUT 128
#define ROWCAP 256
#define SCANCAP 1024
#define EDGECAP 2000000

typedef float vfloat4 __attribute__((ext_vector_type(4)));

// ---------------- threefry2x32 with key (0, 42) --------------------------
__device__ __forceinline__ void threefry_0_42(uint32_t x0, uint32_t x1,
                                              uint32_t& o0, uint32_t& o1) {
  const uint32_t ks0 = 0u;
  const uint32_t ks1 = 42u;
  const uint32_t ks2 = 0x1BD11BDAu ^ 0u ^ 42u;
  x0 += ks0; x1 += ks1;
#define TF_R(r) { x0 += x1; x1 = (x1 << (r)) | (x1 >> (32 - (r))); x1 ^= x0; }
  TF_R(13) TF_R(15) TF_R(26) TF_R(6)
  x0 += ks1; x1 += ks2 + 1u;
  TF_R(17) TF_R(29) TF_R(16) TF_R(24)
  x0 += ks2; x1 += ks0 + 2u;
  TF_R(13) TF_R(15) TF_R(26) TF_R(6)
  x0 += ks0; x1 += ks1 + 3u;
  TF_R(17) TF_R(29) TF_R(16) TF_R(24)
  x0 += ks1; x1 += ks2 + 4u;
  TF_R(13) TF_R(15) TF_R(26) TF_R(6)
  x0 += ks2; x1 += ks0 + 5u;
#undef TF_R
  o0 = x0; o1 = x1;
}

__device__ __forceinline__ bool dropedge_keep(uint32_t t) {
  uint32_t y0, y1;
  threefry_0_42(0u, t, y0, y1);
  uint32_t bits = y0 ^ y1;
  float u = __uint_as_float((bits >> 9) | 0x3f800000u) - 1.0f;
  return u < 0.8f;
}

__device__ __forceinline__ unsigned short f2bf(float v) {
  uint32_t u = __float_as_uint(v);
  u += 0x7fffu + ((u >> 16) & 1u);     // round-to-nearest-even
  return (unsigned short)(u >> 16);
}

// diagonal A3 value: depends only on the keep bit (dist = 1e-6 exactly)
__device__ __forceinline__ float diag_a3(int r) {
  bool keep = dropedge_keep((uint32_t)r * (uint32_t)N + (uint32_t)r);
  float aval = expf(-0.2f * 1e-6f);
  float sg = fmaxf(1.0f / (1.0f + expf(-aval)), 0.1f);
  float bb = keep ? sg : 0.0f;
  return bb + 1.0f;                    // always > 0.6
}

// ---------------- K1: bn_part + W pack + counter zero --------------------
// blocks [0,64): BN partial sums; [64,256): Wc pack; [256,258): bc;
// [258,275): zero deg + nnz_cnt + edge_cnt (contiguous 4097 int4).
__global__ __launch_bounds__(256) void k_pre(
    const float* __restrict__ H,
    const float* __restrict__ Wt, const float* __restrict__ bt,
    const float* __restrict__ Wo, const float* __restrict__ bo,
    float* __restrict__ part_s, float* __restrict__ part_s2,
    float* __restrict__ Wc, float* __restrict__ bc,
    float* __restrict__ deg /* deg + nnz_cnt + edge_cnt contiguous */) {
  int b = blockIdx.x;
  int tid = threadIdx.x;
  if (b < 64) {
    __shared__ float ls[8][DIN];
    __shared__ float ls2[8][DIN];
    int rg = tid >> 5;
    int c4 = tid & 31;
    int rbase = b * 128;
    float s[4] = {0,0,0,0}, s2[4] = {0,0,0,0};
    for (int k = 0; k < 16; ++k) {
      int r = rbase + rg + k * 8;
      float4 h = ((const float4*)(H + (size_t)r * DIN))[c4];
      s[0] += h.x; s2[0] += h.x * h.x;
      s[1] += h.y; s2[1] += h.y * h.y;
      s[2] += h.z; s2[2] += h.z * h.z;
      s[3] += h.w; s2[3] += h.w * h.w;
    }
#pragma unroll
    for (int q = 0; q < 4; ++q) { ls[rg][c4*4+q] = s[q]; ls2[rg][c4*4+q] = s2[q]; }
    __syncthreads();
    if (tid < DIN) {
      float a = 0.f, bb = 0.f;
#pragma unroll
      for (int g = 0; g < 8; ++g) { a += ls[g][tid]; bb += ls2[g][tid]; }
      part_s[b * DIN + tid] = a;
      part_s2[b * DIN + tid] = bb;
    }
  } else if (b < 256) {
    int idx = (b - 64) * 256 + tid;        // [0, 49152)
    int k = idx / 384, c = idx % 384;
    Wc[idx] = (c < 256) ? Wt[(size_t)c * DIN + k] : Wo[(size_t)(c - 256) * DIN + k];
  } else if (b < 258) {
    int c = (b - 256) * 256 + tid;
    if (c < 384) bc[c] = (c < 256) ? bt[c] : bo[c - 256];
  } else {
    int g = (b - 258) * 256 + tid;         // zero 4097 int4 (deg,nnz_cnt,edge_cnt)
    if (g < 4097) ((int4*)deg)[g] = make_int4(0, 0, 0, 0);
  }
}

// ---------------- K2: fused GEMM + A3 zero/diag + A_adj scan -------------
// blocks [0,512): GEMM for 16 rows (BN finalize inlined);
// blocks [512,4608): s=b-512; even s -> zero slab s/2 (4 rows, nt-stores,
//   then analytic diagonal + deg); odd s -> scan slab s/2 (4 rows of the
//   A_adj upper triangle -> packed edge list, one atomic per block).
// No cross-phase dependencies; every stream runs barrier-free.
__global__ __launch_bounds__(256) void k_fused(
    const float* __restrict__ H, const float* __restrict__ A_adj,
    const float* __restrict__ part_s, const float* __restrict__ part_s2,
    const float* __restrict__ gamma, const float* __restrict__ beta,
    const float* __restrict__ Wc, const float* __restrict__ bc,
    unsigned short* __restrict__ Hxh, float* __restrict__ HW,
    float* __restrict__ sq, float* __restrict__ A3,
    float* __restrict__ deg, int* __restrict__ edges,
    int* __restrict__ edge_cnt) {
  int b = blockIdx.x;
  int tid = threadIdx.x;

  if (b >= 512) {
    int s = b - 512;
    if ((s & 1) == 0) {
      // ---- zero slab: 4 rows = 128 KB, nt float4 stores ----
      int z = s >> 1;
      int rbase = z * 4;
      vfloat4* p = (vfloat4*)(A3 + (size_t)rbase * N);
      const vfloat4 zv = {0.f, 0.f, 0.f, 0.f};
#pragma unroll
      for (int it = 0; it < 32; ++it)
        __builtin_nontemporal_store(zv, p + tid + it * 256);
      __syncthreads();                 // drain nt-stores before diag overwrite
      if (tid < 4) {
        int r = rbase + tid;
        float d = diag_a3(r);
        A3[(size_t)r * N + r] = d;
        deg[r] = d;                    // survivors atomically added later
      }
    } else {
      // ---- scan slab: 4 rows of the upper triangle ----
      int sb = s >> 1;
      __shared__ int s_edges[SCANCAP];
      __shared__ int s_cnt;
      __shared__ int s_base;
      if (tid == 0) s_cnt = 0;
      __syncthreads();
      for (int rr = 0; rr < 4; ++rr) {
        int r = sb * 4 + rr;
        const vfloat4* arow = (const vfloat4*)(A_adj + (size_t)r * N);
        int q0 = r >> 2;
        for (int q4 = q0 + tid; q4 < N / 4; q4 += 256) {
          vfloat4 a = __builtin_nontemporal_load(arow + q4);
          int jb = q4 * 4;
          float av[4] = {a.x, a.y, a.z, a.w};
#pragma unroll
          for (int q = 0; q < 4; ++q) {
            int j = jb + q;
            if (av[q] != 0.f && j > r) {
              int pk = (r << 13) | j;
              int p = atomicAdd(&s_cnt, 1);
              if (p < SCANCAP) s_edges[p] = pk;
              else {
                int gp = atomicAdd(edge_cnt, 1);
                if (gp < EDGECAP) edges[gp] = pk;
              }
            }
          }
        }
      }
      __syncthreads();
      int m = min(s_cnt, SCANCAP);
      if (tid == 0) s_base = atomicAdd(edge_cnt, m);
      __syncthreads();
      int base = s_base;
      for (int t = tid; t < m; t += 256)
        if (base + t < EDGECAP) edges[base + t] = s_edges[t];
    }
    return;
  }

  // ---- GEMM block ----
  __shared__ __align__(16) float ssc[DIN];
  __shared__ __align__(16) float ssh[DIN];
  __shared__ float hn[16][DIN];
  if (tid < DIN) {
    float s = 0.f, s2 = 0.f;
    for (int g = 0; g < 64; ++g) { s += part_s[g*DIN+tid]; s2 += part_s2[g*DIN+tid]; }
    float mean = s * (1.0f / N);
    float var  = s2 * (1.0f / N) - mean * mean;
    float sc = rsqrtf(var + 1e-5f) * gamma[tid];
    ssc[tid] = sc;
    ssh[tid] = beta[tid] - mean * sc;
  }
  __syncthreads();
  int base = b * 16;
#pragma unroll
  for (int k = 0; k < 2; ++k) {
    int f = tid + k * 256;
    int r = f >> 5, c4 = f & 31;
    float4 h  = ((const float4*)(H + (size_t)(base + r) * DIN))[c4];
    float4 sc = ((const float4*)ssc)[c4];
    float4 sh = ((const float4*)ssh)[c4];
    h.x = h.x * sc.x + sh.x; h.y = h.y * sc.y + sh.y;
    h.z = h.z * sc.z + sh.z; h.w = h.w * sc.w + sh.w;
    ((float4*)hn[r])[c4] = h;
  }
  __syncthreads();
  int w = tid >> 6, lane = tid & 63;
  int r0 = w * 4;
  float acc[4][6];
#pragma unroll
  for (int r = 0; r < 4; ++r)
#pragma unroll
    for (int q = 0; q < 6; ++q) acc[r][q] = 0.f;

  for (int k4 = 0; k4 < 32; ++k4) {
    float4 h[4];
#pragma unroll
    for (int r = 0; r < 4; ++r) h[r] = ((const float4*)hn[r0 + r])[k4];
#pragma unroll
    for (int kk = 0; kk < 4; ++kk) {
      const float* wrow = Wc + (size_t)(k4 * 4 + kk) * 384 + lane;
      float wv[6];
#pragma unroll
      for (int q = 0; q < 6; ++q) wv[q] = wrow[64 * q];
#pragma unroll
      for (int r = 0; r < 4; ++r) {
        float hs = (kk == 0) ? h[r].x : (kk == 1) ? h[r].y
                 : (kk == 2) ? h[r].z : h[r].w;
#pragma unroll
        for (int q = 0; q < 6; ++q) acc[r][q] += hs * wv[q];
      }
    }
  }
#pragma unroll
  for (int r = 0; r < 4; ++r) {
    int row = base + r0 + r;
    float s = 0.f;
#pragma unroll
    for (int q = 0; q < 4; ++q) {
      float v = acc[r][q] + bc[lane + 64 * q];
      Hxh[(size_t)row * DTH + lane + 64 * q] = f2bf(v);
      s += v * v;
    }
#pragma unroll
    for (int off = 32; off > 0; off >>= 1) s += __shfl_xor(s, off, 64);
    if (lane == 0) sq[row] = s;
#pragma unroll
    for (int q = 4; q < 6; ++q) {
      float v = acc[r][q] + bc[lane + 64 * q];
      HW[(size_t)row * DOUT + lane + 64 * (q - 4)] = v;
    }
  }
}

// ---------------- K3: edge evaluation, 8 lanes per edge ------------------
// Grid-strides the packed edge list. Each 8-lane group computes the 256-dim
// bf16 dot with 4 coalesced uint4 chunks/lane + width-8 shuffle reduce.
// Survivors (rare) scatter both triangles of A3 (zeros committed at the
// kernel boundary -> race-free) and push into the per-row nnz lists.
__global__ __launch_bounds__(256) void k_dot(
    const unsigned short* __restrict__ Hxh, const float* __restrict__ sq,
    const int* __restrict__ edges, const int* __restrict__ edge_cnt,
    float* __restrict__ A3, float* __restrict__ deg,
    int* __restrict__ nnz_cnt, int* __restrict__ nnz_idx,
    float* __restrict__ nnz_val) {
  int cnt = min(*(volatile const int*)edge_cnt, EDGECAP);
  int l = threadIdx.x & 7;
  int g = (blockIdx.x << 5) | (threadIdx.x >> 3);
  int stride = gridDim.x << 5;
  for (int e = g; e < cnt; e += stride) {
    uint32_t pk = (uint32_t)edges[e];
    int i = pk >> 13, j = pk & 8191;
    const uint4* hi = (const uint4*)(Hxh + (size_t)i * DTH);
    const uint4* hj = (const uint4*)(Hxh + (size_t)j * DTH);
    float dot = 0.f;
#pragma unroll
    for (int t = 0; t < 4; ++t) {
      uint4 u = hi[t * 8 + l];
      uint4 v = hj[t * 8 + l];
      dot += __uint_as_float(u.x << 16)         * __uint_as_float(v.x << 16)
           + __uint_as_float(u.x & 0xffff0000u) * __uint_as_float(v.x & 0xffff0000u)
           + __uint_as_float(u.y << 16)         * __uint_as_float(v.y << 16)
           + __uint_as_float(u.y & 0xffff0000u) * __uint_as_float(v.y & 0xffff0000u)
           + __uint_as_float(u.z << 16)         * __uint_as_float(v.z << 16)
           + __uint_as_float(u.z & 0xffff0000u) * __uint_as_float(v.z & 0xffff0000u)
           + __uint_as_float(u.w << 16)         * __uint_as_float(v.w << 16)
           + __uint_as_float(u.w & 0xffff0000u) * __uint_as_float(v.w & 0xffff0000u);
    }
    dot += __shfl_xor(dot, 1, 8);
    dot += __shfl_xor(dot, 2, 8);
    dot += __shfl_xor(dot, 4, 8);
    if (l == 0) {
      float dist = sqrtf(fmaxf(sq[i] + sq[j] - 2.0f * dot, 1e-12f));
      bool keep = dropedge_keep((uint32_t)i * (uint32_t)N + (uint32_t)j);
      float aval = expf(-0.2f * dist);
      float sg = fmaxf(1.0f / (1.0f + expf(-aval)), 0.1f);
      float a2 = keep ? sg : 0.0f;               // i != j: no +1
      float a3v = (a2 > 0.6f) ? a2 : 0.0f;
      if (a3v != 0.f) {
        A3[(size_t)i * N + j] = a3v;
        A3[(size_t)j * N + i] = a3v;
        atomicAdd(&deg[i], a3v);
        atomicAdd(&deg[j], a3v);
        int p = atomicAdd(&nnz_cnt[i], 1);
        if (p < ROWCAP) {
          nnz_idx[(size_t)i * ROWCAP + p] = j;
          nnz_val[(size_t)i * ROWCAP + p] = a3v;
        }
        int p2 = atomicAdd(&nnz_cnt[j], 1);
        if (p2 < ROWCAP) {
          nnz_idx[(size_t)j * ROWCAP + p2] = i;
          nnz_val[(size_t)j * ROWCAP + p2] = a3v;
        }
      }
    }
  }
}

// ---------------- K4: out = lrelu(D^-1/2 A3 D^-1/2 @ HW), 4 rows/block ---
// Diagonal contribution read from A3/deg; lists hold only off-diag survivors.
__global__ __launch_bounds__(256) void k_post(
    const float* __restrict__ HW, const float* __restrict__ deg,
    const int* __restrict__ nnz_cnt, const int* __restrict__ nnz_idx,
    const float* __restrict__ nnz_val, const float* __restrict__ A3,
    float* __restrict__ out) {
  int g = threadIdx.x >> 7;       // 0/1
  int c = threadIdx.x & 127;
#pragma unroll
  for (int k = 0; k < 2; ++k) {
    int i = blockIdx.x * 4 + g * 2 + k;
    float ri = rsqrtf(deg[i]);
    float acc = A3[(size_t)i * N + i] * ri * HW[(size_t)i * DOUT + c];
    int cnt = min(nnz_cnt[i], ROWCAP);
    for (int e = 0; e < cnt; ++e) {
      int j = nnz_idx[(size_t)i * ROWCAP + e];
      float v = nnz_val[(size_t)i * ROWCAP + e];
      acc += v * rsqrtf(deg[j]) * HW[(size_t)j * DOUT + c];
    }
    float o = ri * acc;
    out[(size_t)i * DOUT + c] = (o >= 0.f) ? o : 0.01f * o;
  }
}

// ---------------- launch --------------------------------------------------
extern "C" void kernel_launch(void* const* d_in, const int* in_sizes, int n_in,
                              void* d_out, int out_size, void* d_ws, size_t ws_size,
                              hipStream_t stream) {
  const float* H     = (const float*)d_in[0];
  const float* A_adj = (const float*)d_in[1];
  const float* gamma = (const float*)d_in[2];
  const float* beta  = (const float*)d_in[3];
  const float* Wt    = (const float*)d_in[4];
  const float* bt    = (const float*)d_in[5];
  const float* Wo    = (const float*)d_in[6];
  const float* bo    = (const float*)d_in[7];

  float* out = (float*)d_out;                    // [N, DOUT]
  float* A3  = out + (size_t)N * DOUT;           // [N, N]

  float* ws    = (float*)d_ws;
  unsigned short* Hxh = (unsigned short*)ws;      // N*256 bf16 (= N*128 floats)
  float* sq    = ws + (size_t)N * 128;            // N
  float* HW    = sq + N;                          // N*128
  float* deg   = HW + (size_t)N * DOUT;           // N  (deg,nnz_cnt,edge_cnt contiguous)
  int*   nnz_cnt  = (int*)(deg + N);              // N
  int*   edge_cnt = nnz_cnt + N;                  // 4 (one used)
  int*   nnz_idx  = edge_cnt + 4;                 // N*ROWCAP
  float* nnz_val  = (float*)(nnz_idx + (size_t)N * ROWCAP); // N*ROWCAP
  float* part_s   = nnz_val + (size_t)N * ROWCAP; // 64*128
  float* part_s2  = part_s + 64 * DIN;            // 64*128
  float* Wc       = part_s2 + 64 * DIN;           // 128*384
  float* bc       = Wc + 128 * 384;               // 384
  int*   edges    = (int*)(bc + 384);             // EDGECAP

  k_pre<<<275, 256, 0, stream>>>(H, Wt, bt, Wo, bo, part_s, part_s2, Wc, bc, deg);
  k_fused<<<4608, 256, 0, stream>>>(H, A_adj, part_s, part_s2, gamma, beta, Wc, bc,
                                    Hxh, HW, sq, A3, deg, edges, edge_cnt);
  k_dot<<<2048, 256, 0, stream>>>(Hxh, sq, edges, edge_cnt, A3, deg,
                                  nnz_cnt, nnz_idx, nnz_val);
  k_post<<<N / 4, 256, 0, stream>>>(HW, deg, nnz_cnt, nnz_idx, nnz_val, A3, out);
}

// Round 5
// 467.930 us; speedup vs baseline: 1.0813x; 1.0207x over previous
//
#include <hip/hip_runtime.h>
#include <cstdint>
#include <cstddef>

#define N 8192
#define DIN 128
#define DTH 256
#define DOUT 128
#define ROWCAP 256
#define LISTCAP 256

typedef float vfloat4 __attribute__((ext_vector_type(4)));

// ---------------- threefry2x32 with key (0, 42) --------------------------
__device__ __forceinline__ void threefry_0_42(uint32_t x0, uint32_t x1,
                                              uint32_t& o0, uint32_t& o1) {
  const uint32_t ks0 = 0u;
  const uint32_t ks1 = 42u;
  const uint32_t ks2 = 0x1BD11BDAu ^ 0u ^ 42u;
  x0 += ks0; x1 += ks1;
#define TF_R(r) { x0 += x1; x1 = (x1 << (r)) | (x1 >> (32 - (r))); x1 ^= x0; }
  TF_R(13) TF_R(15) TF_R(26) TF_R(6)
  x0 += ks1; x1 += ks2 + 1u;
  TF_R(17) TF_R(29) TF_R(16) TF_R(24)
  x0 += ks2; x1 += ks0 + 2u;
  TF_R(13) TF_R(15) TF_R(26) TF_R(6)
  x0 += ks0; x1 += ks1 + 3u;
  TF_R(17) TF_R(29) TF_R(16) TF_R(24)
  x0 += ks1; x1 += ks2 + 4u;
  TF_R(13) TF_R(15) TF_R(26) TF_R(6)
  x0 += ks2; x1 += ks0 + 5u;
#undef TF_R
  o0 = x0; o1 = x1;
}

__device__ __forceinline__ bool dropedge_keep(uint32_t t) {
  uint32_t y0, y1;
  threefry_0_42(0u, t, y0, y1);
  uint32_t bits = y0 ^ y1;
  float u = __uint_as_float((bits >> 9) | 0x3f800000u) - 1.0f;
  return u < 0.8f;
}

__device__ __forceinline__ unsigned short f2bf(float v) {
  uint32_t u = __float_as_uint(v);
  u += 0x7fffu + ((u >> 16) & 1u);     // round-to-nearest-even
  return (unsigned short)(u >> 16);
}

// ---------------- K1: fused bn_part + W pack + counter zero --------------
// blocks [0,64): BN partial sums; [64,256): Wc pack; [256,258): bc;
// [258,274): zero deg + nnz_cnt (contiguous 64 KB).
__global__ __launch_bounds__(256) void k_pre(
    const float* __restrict__ H,
    const float* __restrict__ Wt, const float* __restrict__ bt,
    const float* __restrict__ Wo, const float* __restrict__ bo,
    float* __restrict__ part_s, float* __restrict__ part_s2,
    float* __restrict__ Wc, float* __restrict__ bc,
    float* __restrict__ deg /* deg + nnz_cnt contiguous */) {
  int b = blockIdx.x;
  int tid = threadIdx.x;
  if (b < 64) {
    __shared__ float ls[8][DIN];
    __shared__ float ls2[8][DIN];
    int rg = tid >> 5;
    int c4 = tid & 31;
    int rbase = b * 128;
    float s[4] = {0,0,0,0}, s2[4] = {0,0,0,0};
    for (int k = 0; k < 16; ++k) {
      int r = rbase + rg + k * 8;
      float4 h = ((const float4*)(H + (size_t)r * DIN))[c4];
      s[0] += h.x; s2[0] += h.x * h.x;
      s[1] += h.y; s2[1] += h.y * h.y;
      s[2] += h.z; s2[2] += h.z * h.z;
      s[3] += h.w; s2[3] += h.w * h.w;
    }
#pragma unroll
    for (int q = 0; q < 4; ++q) { ls[rg][c4*4+q] = s[q]; ls2[rg][c4*4+q] = s2[q]; }
    __syncthreads();
    if (tid < DIN) {
      float a = 0.f, bb = 0.f;
#pragma unroll
      for (int g = 0; g < 8; ++g) { a += ls[g][tid]; bb += ls2[g][tid]; }
      part_s[b * DIN + tid] = a;
      part_s2[b * DIN + tid] = bb;
    }
  } else if (b < 256) {
    int idx = (b - 64) * 256 + tid;        // [0, 49152)
    int k = idx / 384, c = idx % 384;
    Wc[idx] = (c < 256) ? Wt[(size_t)c * DIN + k] : Wo[(size_t)(c - 256) * DIN + k];
  } else if (b < 258) {
    int c = (b - 256) * 256 + tid;
    if (c < 384) bc[c] = (c < 256) ? bt[c] : bo[c - 256];
  } else {
    int g = (b - 258) * 256 + tid;         // [0, 4096) int4 = 64 KB
    ((int4*)deg)[g] = make_int4(0, 0, 0, 0);
  }
}

// ---------------- K2: GEMM blocks + A3-zero blocks -----------------------
// blocks [0,512): Hxh(bf16)/HW/sq for 16 rows each (BN finalize inlined);
// blocks [512, 512+8192): zero A3 row (b-512) with nontemporal stores.
__global__ __launch_bounds__(256) void k_rows(
    const float* __restrict__ H,
    const float* __restrict__ part_s, const float* __restrict__ part_s2,
    const float* __restrict__ gamma, const float* __restrict__ beta,
    const float* __restrict__ Wc, const float* __restrict__ bc,
    unsigned short* __restrict__ Hxh, float* __restrict__ HW,
    float* __restrict__ sq, float* __restrict__ A3) {
  int tid = threadIdx.x;
  int b = blockIdx.x;
  if (b >= 512) {
    vfloat4* row = (vfloat4*)(A3 + (size_t)(b - 512) * N);
    const vfloat4 z = {0.f, 0.f, 0.f, 0.f};
#pragma unroll
    for (int it = 0; it < 8; ++it)
      __builtin_nontemporal_store(z, row + tid + it * 256);
    return;
  }
  __shared__ __align__(16) float ssc[DIN];
  __shared__ __align__(16) float ssh[DIN];
  __shared__ float hn[16][DIN];   // 8 KB; reads below are wave-broadcast
  // inline BN finalize (identical bit-exact result in every block)
  if (tid < DIN) {
    float s = 0.f, s2 = 0.f;
    for (int g = 0; g < 64; ++g) { s += part_s[g*DIN+tid]; s2 += part_s2[g*DIN+tid]; }
    float mean = s * (1.0f / N);
    float var  = s2 * (1.0f / N) - mean * mean;
    float sc = rsqrtf(var + 1e-5f) * gamma[tid];
    ssc[tid] = sc;
    ssh[tid] = beta[tid] - mean * sc;
  }
  __syncthreads();
  int base = b * 16;
#pragma unroll
  for (int k = 0; k < 2; ++k) {
    int f = tid + k * 256;
    int r = f >> 5, c4 = f & 31;
    float4 h  = ((const float4*)(H + (size_t)(base + r) * DIN))[c4];
    float4 sc = ((const float4*)ssc)[c4];
    float4 sh = ((const float4*)ssh)[c4];
    h.x = h.x * sc.x + sh.x; h.y = h.y * sc.y + sh.y;
    h.z = h.z * sc.z + sh.z; h.w = h.w * sc.w + sh.w;
    ((float4*)hn[r])[c4] = h;
  }
  __syncthreads();
  int w = tid >> 6, lane = tid & 63;
  int r0 = w * 4;
  float acc[4][6];
#pragma unroll
  for (int r = 0; r < 4; ++r)
#pragma unroll
    for (int q = 0; q < 6; ++q) acc[r][q] = 0.f;

  for (int k4 = 0; k4 < 32; ++k4) {
    float4 h[4];
#pragma unroll
    for (int r = 0; r < 4; ++r) h[r] = ((const float4*)hn[r0 + r])[k4];
#pragma unroll
    for (int kk = 0; kk < 4; ++kk) {
      const float* wrow = Wc + (size_t)(k4 * 4 + kk) * 384 + lane;
      float wv[6];
#pragma unroll
      for (int q = 0; q < 6; ++q) wv[q] = wrow[64 * q];
#pragma unroll
      for (int r = 0; r < 4; ++r) {
        float hs = (kk == 0) ? h[r].x : (kk == 1) ? h[r].y
                 : (kk == 2) ? h[r].z : h[r].w;
#pragma unroll
        for (int q = 0; q < 6; ++q) acc[r][q] += hs * wv[q];
      }
    }
  }
#pragma unroll
  for (int r = 0; r < 4; ++r) {
    int row = base + r0 + r;
    float s = 0.f;
#pragma unroll
    for (int q = 0; q < 4; ++q) {
      float v = acc[r][q] + bc[lane + 64 * q];
      Hxh[(size_t)row * DTH + lane + 64 * q] = f2bf(v);
      s += v * v;
    }
#pragma unroll
    for (int off = 32; off > 0; off >>= 1) s += __shfl_xor(s, off, 64);
    if (lane == 0) sq[row] = s;
#pragma unroll
    for (int q = 4; q < 6; ++q) {
      float v = acc[r][q] + bc[lane + 64 * q];
      HW[(size_t)row * DOUT + lane + 64 * (q - 4)] = v;
    }
  }
}

// ---------------- K3: upper-tri edge pass, direct A3 scatter -------------
// A3 rows are fully zeroed by k_rows (previous kernel in stream) before any
// block here runs, so scattered writes of survivors are safe.
// deg[i] is register-accumulated and block-reduced to ONE atomic (the
// baseline issued ~33 serialized same-address atomics per row); mirror
// deg[j] atomics (distinct addresses) are unchanged.
__global__ __launch_bounds__(256) void k_main(
    const float* __restrict__ A_adj, const unsigned short* __restrict__ Hxh,
    const float* __restrict__ sq, float* __restrict__ A3,
    float* __restrict__ deg, int* __restrict__ nnz_cnt,
    int* __restrict__ nnz_idx, float* __restrict__ nnz_val) {
  int i = blockIdx.x;
  int tid = threadIdx.x;
  __shared__ float4 hx4[64];          // hx_i as 64 float4
  __shared__ int   s_list[LISTCAP];
  __shared__ int   s_cnt;
  __shared__ float s_degp[4];
  if (tid == 0) s_cnt = 0;
  ((float*)hx4)[tid] = __uint_as_float(((uint32_t)Hxh[(size_t)i * DTH + tid]) << 16);
  __syncthreads();

  const vfloat4* arow = (const vfloat4*)(A_adj + (size_t)i * N);
  int q0 = i >> 2;
  for (int q4 = q0 + tid; q4 < N / 4; q4 += 256) {
    vfloat4 a = __builtin_nontemporal_load(arow + q4);
    int jb = q4 * 4;
    float av[4] = {a.x, a.y, a.z, a.w};
#pragma unroll
    for (int q = 0; q < 4; ++q) {
      int j = jb + q;
      if (av[q] != 0.f && j >= i) {
        int p = atomicAdd(&s_cnt, 1);
        if (p < LISTCAP) s_list[p] = j;
      }
    }
  }
  __syncthreads();

  int M = min(s_cnt, LISTCAP);
  float sqi = sq[i];
  float dpart = 0.f;
  for (int t = tid; t < M; t += 256) {
    int j = s_list[t];
    bool keep = dropedge_keep((uint32_t)i * (uint32_t)N + (uint32_t)j);
    float dist;
    if (j == i) {
      dist = 1e-6f;                      // exact diagonal: sqrt(clip(0,1e-12))
    } else {
      const uint4* hj = (const uint4*)(Hxh + (size_t)j * DTH);
      float dot = 0.f;
#pragma unroll 8
      for (int c = 0; c < 32; ++c) {
        uint4 u = hj[c];
        float4 f0 = hx4[2 * c], f1 = hx4[2 * c + 1];
        dot += __uint_as_float(u.x << 16) * f0.x
             + __uint_as_float(u.x & 0xffff0000u) * f0.y
             + __uint_as_float(u.y << 16) * f0.z
             + __uint_as_float(u.y & 0xffff0000u) * f0.w
             + __uint_as_float(u.z << 16) * f1.x
             + __uint_as_float(u.z & 0xffff0000u) * f1.y
             + __uint_as_float(u.w << 16) * f1.z
             + __uint_as_float(u.w & 0xffff0000u) * f1.w;
      }
      dist = sqrtf(fmaxf(sqi + sq[j] - 2.0f * dot, 1e-12f));
    }
    float aval = expf(-0.2f * dist);
    float sg = fmaxf(1.0f / (1.0f + expf(-aval)), 0.1f);
    float bb = keep ? sg : 0.0f;
    float a2 = bb + ((i == j) ? 1.0f : 0.0f);
    float a3v = (a2 > 0.6f) ? a2 : 0.0f;
    if (a3v != 0.f) {
      A3[(size_t)i * N + j] = a3v;
      dpart += a3v;                      // deg[i]: reduced once at the end
      int p = atomicAdd(&nnz_cnt[i], 1);
      if (p < ROWCAP) {
        nnz_idx[(size_t)i * ROWCAP + p] = j;
        nnz_val[(size_t)i * ROWCAP + p] = a3v;
      }
      if (j != i) {
        A3[(size_t)j * N + i] = a3v;
        atomicAdd(&deg[j], a3v);
        int p2 = atomicAdd(&nnz_cnt[j], 1);
        if (p2 < ROWCAP) {
          nnz_idx[(size_t)j * ROWCAP + p2] = i;
          nnz_val[(size_t)j * ROWCAP + p2] = a3v;
        }
      }
    }
  }
  // block reduction for deg[i]: one atomic per row instead of ~33
#pragma unroll
  for (int off = 32; off > 0; off >>= 1) dpart += __shfl_xor(dpart, off, 64);
  int w = tid >> 6, lane = tid & 63;
  if (lane == 0) s_degp[w] = dpart;
  __syncthreads();
  if (tid == 0) {
    float d = s_degp[0] + s_degp[1] + s_degp[2] + s_degp[3];
    if (d != 0.f) atomicAdd(&deg[i], d);
  }
}

// ---------------- K4: out = lrelu(D^-1/2 A3 D^-1/2 @ HW) -----------------
__global__ __launch_bounds__(128) void k_post(
    const float* __restrict__ HW, const float* __restrict__ deg,
    const int* __restrict__ nnz_cnt, const int* __restrict__ nnz_idx,
    const float* __restrict__ nnz_val, float* __restrict__ out) {
  int i = blockIdx.x;
  int c = threadIdx.x;      // 128
  int cnt = min(nnz_cnt[i], ROWCAP);
  float acc = 0.f;
  for (int e = 0; e < cnt; ++e) {
    int j = nnz_idx[(size_t)i * ROWCAP + e];
    float v = nnz_val[(size_t)i * ROWCAP + e];
    acc += v * rsqrtf(deg[j]) * HW[(size_t)j * DOUT + c];
  }
  float o = rsqrtf(deg[i]) * acc;
  out[(size_t)i * DOUT + c] = (o >= 0.f) ? o : 0.01f * o;
}

// ---------------- launch --------------------------------------------------
extern "C" void kernel_launch(void* const* d_in, const int* in_sizes, int n_in,
                              void* d_out, int out_size, void* d_ws, size_t ws_size,
                              hipStream_t stream) {
  const float* H     = (const float*)d_in[0];
  const float* A_adj = (const float*)d_in[1];
  const float* gamma = (const float*)d_in[2];
  const float* beta  = (const float*)d_in[3];
  const float* Wt    = (const float*)d_in[4];
  const float* bt    = (const float*)d_in[5];
  const float* Wo    = (const float*)d_in[6];
  const float* bo    = (const float*)d_in[7];

  float* out = (float*)d_out;                    // [N, DOUT]
  float* A3  = out + (size_t)N * DOUT;           // [N, N]

  float* ws    = (float*)d_ws;
  unsigned short* Hxh = (unsigned short*)ws;      // N*256 bf16 (= N*128 floats)
  float* sq    = ws + (size_t)N * 128;            // N
  float* HW    = sq + N;                          // N*128
  float* deg   = HW + (size_t)N * DOUT;           // N   (deg+cnt contiguous!)
  int*   nnz_cnt = (int*)(deg + N);               // N
  int*   nnz_idx = nnz_cnt + N;                   // N*ROWCAP
  float* nnz_val = (float*)(nnz_idx + (size_t)N * ROWCAP); // N*ROWCAP
  float* part_s  = nnz_val + (size_t)N * ROWCAP;  // 64*128
  float* part_s2 = part_s + 64 * DIN;             // 64*128
  float* Wc      = part_s2 + 64 * DIN;            // 128*384
  float* bc      = Wc + 128 * 384;                // 384

  k_pre<<<274, 256, 0, stream>>>(H, Wt, bt, Wo, bo, part_s, part_s2, Wc, bc, deg);
  k_rows<<<512 + N, 256, 0, stream>>>(H, part_s, part_s2, gamma, beta, Wc, bc,
                                      Hxh, HW, sq, A3);
  k_main<<<N, 256, 0, stream>>>(A_adj, Hxh, sq, A3, deg, nnz_cnt, nnz_idx, nnz_val);
  k_post<<<N, DOUT, 0, stream>>>(HW, deg, nnz_cnt, nnz_idx, nnz_val, out);
}